// Round 7
// baseline (1119.266 us; speedup 1.0000x reference)
//
#include <hip/hip_runtime.h>

#define NUM_USERS 50000
#define NUM_ITEMS 100000
#define N_NODES   150000
#define EMBED     64
#define BATCH     4096
#define NNZ       2400000
#define NB        586   // ceil(N_NODES/256)

__device__ __forceinline__ float bf2f(unsigned short u) {
    union { unsigned int u32; float f; } v; v.u32 = ((unsigned int)u) << 16; return v.f;
}
__device__ __forceinline__ float getf(const void* p, int i, int fbf) {
    if (fbf) return bf2f(((const unsigned short*)p)[i]);
    return ((const float*)p)[i];
}
__device__ __forceinline__ int geti(const void* p, int i, int i64) {
    if (i64) return (int)(((const long long*)p)[i]);
    return ((const int*)p)[i];
}
__device__ __forceinline__ int clampi(int v, int lo, int hi) {
    return v < lo ? lo : (v > hi ? hi : v);
}

// -------- dtype probes --------
__global__ void k_flags_r18(const unsigned short* __restrict__ ev,
                            const void* __restrict__ er, int* __restrict__ fl) {
    if (threadIdx.x == 0 && blockIdx.x == 0) {
        int good = 0;
        for (int i = 0; i < 64; ++i) {
            float f = bf2f(ev[i]);
            if (f >= 0.0f && f <= 0.011f) good++;
        }
        fl[0] = (good >= 60) ? 1 : 0;
        int ok = 0;
        for (int i = 0; i < 64; ++i) {
            long long v = ((const long long*)er)[i];
            if (v >= 0 && v < (long long)N_NODES) ok++;
        }
        fl[1] = (ok >= 60) ? 1 : 0;
    }
}

// -------- E0 = concat --------
__global__ void k_init_r18(const void* __restrict__ eu, const void* __restrict__ ei,
                           const int* __restrict__ fl, float* __restrict__ E) {
    int fbf = fl[0];
    int i = blockIdx.x * 256 + threadIdx.x;
    if (i < N_NODES * EMBED) {
        int r = i >> 6;
        float v;
        if (r < NUM_USERS) v = getf(eu, i, fbf);
        else               v = getf(ei, i - NUM_USERS * EMBED, fbf);
        E[i] = v;
    }
}

// ============ CSR build ============
__global__ __launch_bounds__(256) void k_count_r18(const void* __restrict__ er,
                                                   const int* __restrict__ fl,
                                                   int* __restrict__ cnt) {
    int e = blockIdx.x * 256 + threadIdx.x;
    if (e >= NNZ) return;
    int r = clampi(geti(er, e, fl[1]), 0, N_NODES - 1);
    atomicAdd(&cnt[r], 1);
}

__global__ __launch_bounds__(256) void k_scanA_r18(const int* __restrict__ cnt,
                                                   int* __restrict__ bsum) {
    int i = blockIdx.x * 256 + threadIdx.x;
    int v = (i < N_NODES) ? cnt[i] : 0;
    #pragma unroll
    for (int d = 1; d < 64; d <<= 1) v += __shfl_xor(v, d, 64);
    __shared__ int sh[4];
    if ((threadIdx.x & 63) == 0) sh[threadIdx.x >> 6] = v;
    __syncthreads();
    if (threadIdx.x == 0) bsum[blockIdx.x] = sh[0] + sh[1] + sh[2] + sh[3];
}

__global__ __launch_bounds__(1024) void k_scanB_r18(int* __restrict__ bsum) {
    __shared__ int sh[1024];
    int t = threadIdx.x;
    if (t < NB) sh[t] = bsum[t];
    __syncthreads();
    if (t == 0) {
        int run = 0;
        for (int i = 0; i < NB; ++i) { int x = sh[i]; sh[i] = run; run += x; }
    }
    __syncthreads();
    if (t < NB) bsum[t] = sh[t];
}

__global__ __launch_bounds__(256) void k_scanC_r18(const int* __restrict__ cnt,
                                                   const int* __restrict__ bsum,
                                                   int* __restrict__ rowptr) {
    __shared__ int sh[256];
    int i = blockIdx.x * 256 + threadIdx.x;
    int t = threadIdx.x;
    sh[t] = (i < N_NODES) ? cnt[i] : 0;
    __syncthreads();
    if (t == 0) {
        int run = bsum[blockIdx.x];
        for (int k = 0; k < 256; ++k) { int x = sh[k]; sh[k] = run; run += x; }
    }
    __syncthreads();
    if (i < N_NODES) rowptr[i] = sh[t];
    if (i == 0) rowptr[N_NODES] = NNZ;
}

// scatter edges into CSR slots — packed int2 {col, val_bits}
__global__ __launch_bounds__(256) void k_scatter_r18(const void* __restrict__ ev,
                                                     const void* __restrict__ er,
                                                     const void* __restrict__ ec,
                                                     const int* __restrict__ fl,
                                                     const int* __restrict__ rowptr,
                                                     int* __restrict__ cur,
                                                     int2* __restrict__ colcv) {
    int e = blockIdx.x * 256 + threadIdx.x;
    if (e >= NNZ) return;
    int i64 = fl[1], fbf = fl[0];
    int r = clampi(geti(er, e, i64), 0, N_NODES - 1);
    int c = clampi(geti(ec, e, i64), 0, N_NODES - 1);
    float v = getf(ev, e, fbf);
    int p = rowptr[r] + atomicAdd(&cur[r], 1);
    colcv[p] = make_int2(c, __float_as_int(v));
}

// ============ FUSED: gather (CSR) -> LE in LDS -> MLP -> E_out ============
// gather: lane = 16*g + q; each float4 load fetches 4 edges' rows (verified r17)
// mlp:    identity (LE+E)@W1^T + LE@W2^T = LE@(W1+W2)^T + E@W1^T (verified r16)
//         XA = LE -> w12r ;  XB = E -> w1r
__global__ __launch_bounds__(256) void k_fuse_r18(const int* __restrict__ rowptr,
                                                  const int2* __restrict__ colcv,
                                                  const float* __restrict__ Ein,
                                                  float* __restrict__ Eout,
                                                  const void* __restrict__ W1,
                                                  const void* __restrict__ B1,
                                                  const void* __restrict__ W2,
                                                  const void* __restrict__ B2,
                                                  const int* __restrict__ fl, int layer) {
    __shared__ float4 XA[4][16];   // per-wave slot: LE (64 floats)
    __shared__ float4 XB[4][16];   // per-wave slot: E row
    const int fbf  = fl[0];
    const int wofs = layer * EMBED * EMBED;
    const int bofs = layer * EMBED;
    const int lane = threadIdx.x & 63;
    const int w    = threadIdx.x >> 6;
    const int g    = lane >> 4;    // edge group (0..3)
    const int q    = lane & 15;    // column quarter

    // per-thread weight registers: w1r[k] = W1[lane,k]; w12r[k] = W1[lane,k]+W2[lane,k]
    float w1r[64], w12r[64];
    if (fbf) {
        const unsigned short* p1 = (const unsigned short*)W1 + wofs + lane * 64;
        const unsigned short* p2 = (const unsigned short*)W2 + wofs + lane * 64;
        #pragma unroll
        for (int t = 0; t < 16; ++t) {
            ushort4 a = reinterpret_cast<const ushort4*>(p1)[t];
            ushort4 b = reinterpret_cast<const ushort4*>(p2)[t];
            float f0 = bf2f(a.x), f1 = bf2f(a.y), f2 = bf2f(a.z), f3 = bf2f(a.w);
            w1r[4*t+0] = f0; w1r[4*t+1] = f1; w1r[4*t+2] = f2; w1r[4*t+3] = f3;
            w12r[4*t+0] = f0 + bf2f(b.x); w12r[4*t+1] = f1 + bf2f(b.y);
            w12r[4*t+2] = f2 + bf2f(b.z); w12r[4*t+3] = f3 + bf2f(b.w);
        }
    } else {
        const float* p1 = (const float*)W1 + wofs + lane * 64;
        const float* p2 = (const float*)W2 + wofs + lane * 64;
        #pragma unroll
        for (int t = 0; t < 16; ++t) {
            float4 a = reinterpret_cast<const float4*>(p1)[t];
            float4 b = reinterpret_cast<const float4*>(p2)[t];
            w1r[4*t+0] = a.x; w1r[4*t+1] = a.y; w1r[4*t+2] = a.z; w1r[4*t+3] = a.w;
            w12r[4*t+0] = a.x + b.x; w12r[4*t+1] = a.y + b.y;
            w12r[4*t+2] = a.z + b.z; w12r[4*t+3] = a.w + b.w;
        }
    }
    const float bias = getf(B1, bofs + lane, fbf) + getf(B2, bofs + lane, fbf);

    const int gw = blockIdx.x * 4 + w;
    const int nw = gridDim.x * 4;

    for (int row = gw; row < N_NODES; row += nw) {
        const int s = rowptr[row];
        const int e = rowptr[row + 1];
        float ee = Ein[row * EMBED + lane];   // issue early; used after gather

        // ---- gather LE[row] (4 edges per load instruction) ----
        float4 acc = make_float4(0.f, 0.f, 0.f, 0.f);
        for (int base = s; base < e; base += 64) {
            int idx = base + lane;
            int2 cv = make_int2(0, 0);
            if (idx < e) cv = colcv[idx];
            int m = e - base; if (m > 64) m = 64;
            for (int j = 0; j < m; j += 8) {
                int i0 = j + g;
                int i1 = j + 4 + g;
                bool v0 = i0 < m;
                bool v1 = i1 < m;
                int   c0 = __shfl(cv.x, i0, 64);
                float f0 = __int_as_float(__shfl(cv.y, i0, 64));
                int   c1 = __shfl(cv.x, i1, 64);
                float f1 = __int_as_float(__shfl(cv.y, i1, 64));
                c0 = v0 ? c0 : 0;  f0 = v0 ? f0 : 0.0f;
                c1 = v1 ? c1 : 0;  f1 = v1 ? f1 : 0.0f;
                float4 p0 = *reinterpret_cast<const float4*>(&Ein[c0 * EMBED + 4 * q]);
                float4 p1 = *reinterpret_cast<const float4*>(&Ein[c1 * EMBED + 4 * q]);
                acc.x = fmaf(f0, p0.x, acc.x);
                acc.y = fmaf(f0, p0.y, acc.y);
                acc.z = fmaf(f0, p0.z, acc.z);
                acc.w = fmaf(f0, p0.w, acc.w);
                acc.x = fmaf(f1, p1.x, acc.x);
                acc.y = fmaf(f1, p1.y, acc.y);
                acc.z = fmaf(f1, p1.z, acc.z);
                acc.w = fmaf(f1, p1.w, acc.w);
            }
        }
        #pragma unroll
        for (int d = 16; d < 64; d <<= 1) {
            acc.x += __shfl_xor(acc.x, d, 64);
            acc.y += __shfl_xor(acc.y, d, 64);
            acc.z += __shfl_xor(acc.z, d, 64);
            acc.w += __shfl_xor(acc.w, d, 64);
        }

        // ---- stage LE and E-row into the wave's LDS broadcast slots ----
        if (g == 0) XA[w][q] = acc;            // LE  -> pairs with w12r
        ((float*)&XB[w][0])[lane] = ee;        // E   -> pairs with w1r

        // ---- MLP + leaky + row-norm ----
        float acc0 = bias, acc1 = 0.0f;
        #pragma unroll
        for (int t = 0; t < 16; ++t) {
            float4 a = XA[w][t];   // wave-uniform ds_read_b128 broadcast
            float4 b = XB[w][t];
            acc0 = fmaf(a.x, w12r[4*t+0], acc0);
            acc1 = fmaf(b.x, w1r [4*t+0], acc1);
            acc0 = fmaf(a.y, w12r[4*t+1], acc0);
            acc1 = fmaf(b.y, w1r [4*t+1], acc1);
            acc0 = fmaf(a.z, w12r[4*t+2], acc0);
            acc1 = fmaf(b.z, w1r [4*t+2], acc1);
            acc0 = fmaf(a.w, w12r[4*t+3], acc0);
            acc1 = fmaf(b.w, w1r [4*t+3], acc1);
        }
        float av = acc0 + acc1;
        float h = (av > 0.0f) ? av : 0.2f * av;

        float sq = h * h;
        #pragma unroll
        for (int d = 1; d < 64; d <<= 1) sq += __shfl_xor(sq, d, 64);
        const float inv = 1.0f / fmaxf(sqrtf(sq), 1e-12f);

        Eout[row * EMBED + lane] = h * inv;
    }
}

// -------- fallback atomic edge pass (small-ws path) --------
__global__ __launch_bounds__(256) void k_edge_r18(const void* __restrict__ ev,
                                                  const void* __restrict__ er,
                                                  const void* __restrict__ ec,
                                                  const int* __restrict__ fl,
                                                  const float* __restrict__ E,
                                                  float* __restrict__ LE) {
    int fbf = fl[0];
    int i64 = fl[1];
    int e = blockIdx.x * 4 + (threadIdx.x >> 6);
    int lane = threadIdx.x & 63;
    if (e >= NNZ) return;
    int r = clampi(geti(er, e, i64), 0, N_NODES - 1);
    int c = clampi(geti(ec, e, i64), 0, N_NODES - 1);
    float v = getf(ev, e, fbf);
    atomicAdd(&LE[r * EMBED + lane], v * E[c * EMBED + lane]);
}

// -------- fallback dense layer (in-place E), verified r16/r17 structure --------
__global__ __launch_bounds__(256) void k_mlpfb_r18(float* __restrict__ E,
                                                   const float* __restrict__ LE,
                                                   const void* __restrict__ W1,
                                                   const void* __restrict__ B1,
                                                   const void* __restrict__ W2,
                                                   const void* __restrict__ B2,
                                                   const int* __restrict__ fl, int layer) {
    __shared__ float4 XA[4][16];
    __shared__ float4 XB[4][16];
    const int fbf  = fl[0];
    const int wofs = layer * EMBED * EMBED;
    const int bofs = layer * EMBED;
    const int lane = threadIdx.x & 63;
    const int w    = threadIdx.x >> 6;

    float w1r[64], w12r[64];
    if (fbf) {
        const unsigned short* p1 = (const unsigned short*)W1 + wofs + lane * 64;
        const unsigned short* p2 = (const unsigned short*)W2 + wofs + lane * 64;
        #pragma unroll
        for (int t = 0; t < 16; ++t) {
            ushort4 a = reinterpret_cast<const ushort4*>(p1)[t];
            ushort4 b = reinterpret_cast<const ushort4*>(p2)[t];
            float f0 = bf2f(a.x), f1 = bf2f(a.y), f2 = bf2f(a.z), f3 = bf2f(a.w);
            w1r[4*t+0] = f0; w1r[4*t+1] = f1; w1r[4*t+2] = f2; w1r[4*t+3] = f3;
            w12r[4*t+0] = f0 + bf2f(b.x); w12r[4*t+1] = f1 + bf2f(b.y);
            w12r[4*t+2] = f2 + bf2f(b.z); w12r[4*t+3] = f3 + bf2f(b.w);
        }
    } else {
        const float* p1 = (const float*)W1 + wofs + lane * 64;
        const float* p2 = (const float*)W2 + wofs + lane * 64;
        #pragma unroll
        for (int t = 0; t < 16; ++t) {
            float4 a = reinterpret_cast<const float4*>(p1)[t];
            float4 b = reinterpret_cast<const float4*>(p2)[t];
            w1r[4*t+0] = a.x; w1r[4*t+1] = a.y; w1r[4*t+2] = a.z; w1r[4*t+3] = a.w;
            w12r[4*t+0] = a.x + b.x; w12r[4*t+1] = a.y + b.y;
            w12r[4*t+2] = a.z + b.z; w12r[4*t+3] = a.w + b.w;
        }
    }
    const float bias = getf(B1, bofs + lane, fbf) + getf(B2, bofs + lane, fbf);

    const int gw = blockIdx.x * 4 + w;
    const int nw = gridDim.x * 4;
    for (int row = gw; row < N_NODES; row += nw) {
        float le = LE[row * EMBED + lane];
        float ee = E[row * EMBED + lane];
        ((float*)&XA[w][0])[lane] = le;
        ((float*)&XB[w][0])[lane] = ee;
        float acc0 = bias, acc1 = 0.0f;
        #pragma unroll
        for (int t = 0; t < 16; ++t) {
            float4 a = XA[w][t];
            float4 b = XB[w][t];
            acc0 = fmaf(a.x, w12r[4*t+0], acc0);
            acc1 = fmaf(b.x, w1r [4*t+0], acc1);
            acc0 = fmaf(a.y, w12r[4*t+1], acc0);
            acc1 = fmaf(b.y, w1r [4*t+1], acc1);
            acc0 = fmaf(a.z, w12r[4*t+2], acc0);
            acc1 = fmaf(b.z, w1r [4*t+2], acc1);
            acc0 = fmaf(a.w, w12r[4*t+3], acc0);
            acc1 = fmaf(b.w, w1r [4*t+3], acc1);
        }
        float av = acc0 + acc1;
        float h = (av > 0.0f) ? av : 0.2f * av;
        float sq = h * h;
        #pragma unroll
        for (int d = 1; d < 64; d <<= 1) sq += __shfl_xor(sq, d, 64);
        const float inv = 1.0f / fmaxf(sqrtf(sq), 1e-12f);
        E[row * EMBED + lane] = h * inv;
    }
}

// -------- gather batch rows into output --------
__global__ void k_pick_r18(const float* __restrict__ E, const void* __restrict__ bu,
                           const void* __restrict__ bp, const void* __restrict__ bn,
                           const int* __restrict__ fl,
                           float* __restrict__ out, int stage) {
    int i64 = fl[1];
    int i = blockIdx.x * 256 + threadIdx.x;
    if (i >= 3 * BATCH * EMBED) return;
    int c = i & 63;
    int row = i >> 6;
    int o = row >> 12;
    int b = row & 4095;
    int idx;
    if (o == 0)      idx = geti(bu, b, i64);
    else if (o == 1) idx = geti(bp, b, i64);
    else             idx = geti(bn, b, i64);
    int src;
    if (o == 0) src = clampi(idx, 0, NUM_USERS - 1);
    else        src = NUM_USERS + clampi(idx, 0, NUM_ITEMS - 1);
    int pos = o * (BATCH * 256) + b * 256 + stage * 64 + c;
    out[pos] = E[src * EMBED + c];
}

// -------- launch --------
extern "C" void kernel_launch(void* const* d_in, const int* in_sizes, int n_in,
                              void* d_out, int out_size, void* d_ws, size_t ws_size,
                              hipStream_t stream) {
    const void* edge_val = d_in[0];
    const void* emb_u    = d_in[1];
    const void* emb_i    = d_in[2];
    const void* W1w      = d_in[3];
    const void* W1b      = d_in[4];
    const void* W2w      = d_in[5];
    const void* W2b      = d_in[6];
    const void* erow     = d_in[7];
    const void* ecol     = d_in[8];
    const void* bu       = d_in[9];
    const void* bp       = d_in[10];
    const void* bn       = d_in[11];

    const size_t EB   = (size_t)N_NODES * EMBED * sizeof(float);   // 38.4 MB
    const size_t RPB  = 600064;                                     // rowptr
    const size_t CNB  = 600064;                                     // cnt/cursor
    const size_t BSB  = 4096;                                       // block sums
    const size_t CVB2 = (size_t)NNZ * sizeof(int2);                 // 19.2 MB packed (c,v)

    const size_t need_old = 256 + 2 * EB;
    const size_t need_csr = 256 + 2 * EB + RPB + CNB + BSB + CVB2;
    if (ws_size < need_old) return;   // zero-output signature

    char* ws = (char*)d_ws;
    int*   fl     = (int*)ws;
    float* E0     = (float*)(ws + 256);
    float* E1     = (float*)(ws + 256 + EB);       // ping-pong / fallback-LE
    int*   rowptr = (int*)(ws + 256 + 2 * EB);
    int*   cnt    = (int*)(ws + 256 + 2 * EB + RPB);
    int*   bsum   = (int*)(ws + 256 + 2 * EB + RPB + CNB);
    int2*  colcv  = (int2*)(ws + 256 + 2 * EB + RPB + CNB + BSB);
    float* out    = (float*)d_out;

    const bool use_csr = (ws_size >= need_csr);

    k_flags_r18<<<1, 64, 0, stream>>>((const unsigned short*)edge_val, erow, fl);

    k_init_r18<<<(N_NODES * EMBED + 255) / 256, 256, 0, stream>>>(emb_u, emb_i, fl, E0);

    if (use_csr) {
        hipMemsetAsync(cnt, 0, CNB, stream);
        k_count_r18<<<(NNZ + 255) / 256, 256, 0, stream>>>(erow, fl, cnt);
        k_scanA_r18<<<NB, 256, 0, stream>>>(cnt, bsum);
        k_scanB_r18<<<1, 1024, 0, stream>>>(bsum);
        k_scanC_r18<<<NB, 256, 0, stream>>>(cnt, bsum, rowptr);
        hipMemsetAsync(cnt, 0, CNB, stream);
        k_scatter_r18<<<(NNZ + 255) / 256, 256, 0, stream>>>(edge_val, erow, ecol, fl,
                                                             rowptr, cnt, colcv);
    }

    k_pick_r18<<<(3 * BATCH * EMBED + 255) / 256, 256, 0, stream>>>(E0, bu, bp, bn, fl, out, 0);

    float* Ecur = E0;
    float* Enxt = E1;
    for (int l = 0; l < 3; ++l) {
        if (use_csr) {
            k_fuse_r18<<<3072, 256, 0, stream>>>(rowptr, colcv, Ecur, Enxt,
                                                 W1w, W1b, W2w, W2b, fl, l);
            float* tmp = Ecur; Ecur = Enxt; Enxt = tmp;
        } else {
            hipMemsetAsync(E1, 0, EB, stream);
            k_edge_r18<<<(NNZ + 3) / 4, 256, 0, stream>>>(edge_val, erow, ecol, fl, E0, E1);
            k_mlpfb_r18<<<1280, 256, 0, stream>>>(E0, E1, W1w, W1b, W2w, W2b, fl, l);
            // Ecur stays E0 in fallback
        }
        k_pick_r18<<<(3 * BATCH * EMBED + 255) / 256, 256, 0, stream>>>(Ecur, bu, bp, bn, fl, out, l + 1);
    }
}

// Round 8
// 884.394 us; speedup vs baseline: 1.2656x; 1.2656x over previous
//
#include <hip/hip_runtime.h>
#include <hip/hip_fp16.h>

#define NUM_USERS 50000
#define NUM_ITEMS 100000
#define N_NODES   150000
#define EMBED     64
#define BATCH     4096
#define NNZ       2400000
#define NB        586   // ceil(N_NODES/256)

__device__ __forceinline__ float bf2f(unsigned short u) {
    union { unsigned int u32; float f; } v; v.u32 = ((unsigned int)u) << 16; return v.f;
}
__device__ __forceinline__ float getf(const void* p, int i, int fbf) {
    if (fbf) return bf2f(((const unsigned short*)p)[i]);
    return ((const float*)p)[i];
}
__device__ __forceinline__ int geti(const void* p, int i, int i64) {
    if (i64) return (int)(((const long long*)p)[i]);
    return ((const int*)p)[i];
}
__device__ __forceinline__ int clampi(int v, int lo, int hi) {
    return v < lo ? lo : (v > hi ? hi : v);
}
__device__ __forceinline__ float h2f(unsigned short u) {
    return __half2float(__ushort_as_half(u));
}
__device__ __forceinline__ unsigned short f2h(float f) {
    return __half_as_ushort(__float2half(f));
}

// -------- dtype probes --------
__global__ void k_flags_r19(const unsigned short* __restrict__ ev,
                            const void* __restrict__ er, int* __restrict__ fl) {
    if (threadIdx.x == 0 && blockIdx.x == 0) {
        int good = 0;
        for (int i = 0; i < 64; ++i) {
            float f = bf2f(ev[i]);
            if (f >= 0.0f && f <= 0.011f) good++;
        }
        fl[0] = (good >= 60) ? 1 : 0;
        int ok = 0;
        for (int i = 0; i < 64; ++i) {
            long long v = ((const long long*)er)[i];
            if (v >= 0 && v < (long long)N_NODES) ok++;
        }
        fl[1] = (ok >= 60) ? 1 : 0;
    }
}

// -------- E0 = concat(embed_user, embed_item) -> fp16 --------
__global__ void k_init_r19(const void* __restrict__ eu, const void* __restrict__ ei,
                           const int* __restrict__ fl, unsigned short* __restrict__ Eh) {
    int fbf = fl[0];
    int i = blockIdx.x * 256 + threadIdx.x;
    if (i < N_NODES * EMBED) {
        int r = i >> 6;
        float v;
        if (r < NUM_USERS) v = getf(eu, i, fbf);
        else               v = getf(ei, i - NUM_USERS * EMBED, fbf);
        Eh[i] = f2h(v);
    }
}

// ============ CSR build ============
__global__ __launch_bounds__(256) void k_count_r19(const void* __restrict__ er,
                                                   const int* __restrict__ fl,
                                                   int* __restrict__ cnt) {
    int e = blockIdx.x * 256 + threadIdx.x;
    if (e >= NNZ) return;
    int r = clampi(geti(er, e, fl[1]), 0, N_NODES - 1);
    atomicAdd(&cnt[r], 1);
}

__global__ __launch_bounds__(256) void k_scanA_r19(const int* __restrict__ cnt,
                                                   int* __restrict__ bsum) {
    int i = blockIdx.x * 256 + threadIdx.x;
    int v = (i < N_NODES) ? cnt[i] : 0;
    #pragma unroll
    for (int d = 1; d < 64; d <<= 1) v += __shfl_xor(v, d, 64);
    __shared__ int sh[4];
    if ((threadIdx.x & 63) == 0) sh[threadIdx.x >> 6] = v;
    __syncthreads();
    if (threadIdx.x == 0) bsum[blockIdx.x] = sh[0] + sh[1] + sh[2] + sh[3];
}

__global__ __launch_bounds__(1024) void k_scanB_r19(int* __restrict__ bsum) {
    __shared__ int sh[1024];
    int t = threadIdx.x;
    if (t < NB) sh[t] = bsum[t];
    __syncthreads();
    if (t == 0) {
        int run = 0;
        for (int i = 0; i < NB; ++i) { int x = sh[i]; sh[i] = run; run += x; }
    }
    __syncthreads();
    if (t < NB) bsum[t] = sh[t];
}

__global__ __launch_bounds__(256) void k_scanC_r19(const int* __restrict__ cnt,
                                                   const int* __restrict__ bsum,
                                                   int* __restrict__ rowptr) {
    __shared__ int sh[256];
    int i = blockIdx.x * 256 + threadIdx.x;
    int t = threadIdx.x;
    sh[t] = (i < N_NODES) ? cnt[i] : 0;
    __syncthreads();
    if (t == 0) {
        int run = bsum[blockIdx.x];
        for (int k = 0; k < 256; ++k) { int x = sh[k]; sh[k] = run; run += x; }
    }
    __syncthreads();
    if (i < N_NODES) rowptr[i] = sh[t];
    if (i == 0) rowptr[N_NODES] = NNZ;
}

// scatter edges into CSR slots — packed int2 {col, val_bits}
__global__ __launch_bounds__(256) void k_scatter_r19(const void* __restrict__ ev,
                                                     const void* __restrict__ er,
                                                     const void* __restrict__ ec,
                                                     const int* __restrict__ fl,
                                                     const int* __restrict__ rowptr,
                                                     int* __restrict__ cur,
                                                     int2* __restrict__ colcv) {
    int e = blockIdx.x * 256 + threadIdx.x;
    if (e >= NNZ) return;
    int i64 = fl[1], fbf = fl[0];
    int r = clampi(geti(er, e, i64), 0, N_NODES - 1);
    int c = clampi(geti(ec, e, i64), 0, N_NODES - 1);
    float v = getf(ev, e, fbf);
    int p = rowptr[r] + atomicAdd(&cur[r], 1);
    colcv[p] = make_int2(c, __float_as_int(v));
}

// ============ gather: LEh[r] = sum val*Eh[col] — fp16 rows, 4 edges/load ============
// lane = 16*g + q : g = edge group (0..3), q = column quarter (cols 4q..4q+3)
// Eh row = 128 B; lane loads ushort4 (8 B); one instr = 4 full rows.
__global__ __launch_bounds__(256) void k_gath_r19(const int* __restrict__ rowptr,
                                                  const int2* __restrict__ colcv,
                                                  const unsigned short* __restrict__ Eh,
                                                  unsigned short* __restrict__ LEh) {
    int r = blockIdx.x * 4 + (threadIdx.x >> 6);
    if (r >= N_NODES) return;
    const int lane = threadIdx.x & 63;
    const int g = lane >> 4;
    const int q = lane & 15;
    const int s = rowptr[r];
    const int e = rowptr[r + 1];

    float a0 = 0.f, a1 = 0.f, a2 = 0.f, a3 = 0.f;

    for (int base = s; base < e; base += 64) {
        int idx = base + lane;
        int2 cv = make_int2(0, 0);
        if (idx < e) cv = colcv[idx];
        int m = e - base; if (m > 64) m = 64;

        for (int j = 0; j < m; j += 8) {
            int i0 = j + g;
            int i1 = j + 4 + g;
            bool v0 = i0 < m;
            bool v1 = i1 < m;
            int   c0 = __shfl(cv.x, i0, 64);
            float f0 = __int_as_float(__shfl(cv.y, i0, 64));
            int   c1 = __shfl(cv.x, i1, 64);
            float f1 = __int_as_float(__shfl(cv.y, i1, 64));
            c0 = v0 ? c0 : 0;  f0 = v0 ? f0 : 0.0f;
            c1 = v1 ? c1 : 0;  f1 = v1 ? f1 : 0.0f;
            ushort4 p0 = *reinterpret_cast<const ushort4*>(&Eh[c0 * EMBED + 4 * q]);
            ushort4 p1 = *reinterpret_cast<const ushort4*>(&Eh[c1 * EMBED + 4 * q]);
            a0 = fmaf(f0, h2f(p0.x), a0);
            a1 = fmaf(f0, h2f(p0.y), a1);
            a2 = fmaf(f0, h2f(p0.z), a2);
            a3 = fmaf(f0, h2f(p0.w), a3);
            a0 = fmaf(f1, h2f(p1.x), a0);
            a1 = fmaf(f1, h2f(p1.y), a1);
            a2 = fmaf(f1, h2f(p1.z), a2);
            a3 = fmaf(f1, h2f(p1.w), a3);
        }
    }

    #pragma unroll
    for (int d = 16; d < 64; d <<= 1) {
        a0 += __shfl_xor(a0, d, 64);
        a1 += __shfl_xor(a1, d, 64);
        a2 += __shfl_xor(a2, d, 64);
        a3 += __shfl_xor(a3, d, 64);
    }
    if (g == 0) {
        ushort4 o;
        o.x = f2h(a0); o.y = f2h(a1); o.z = f2h(a2); o.w = f2h(a3);
        *reinterpret_cast<ushort4*>(&LEh[r * EMBED + 4 * q]) = o;
    }
}

// -------- dense layer: wave-per-row, weights in regs, x broadcast via LDS b128 --------
// Identity: (LE+E)@W1^T + LE@W2^T + b = LE@(W1+W2)^T + E@W1^T + b
// XA = LE -> w12r ; XB = E -> w1r   (verified r16/r17)
__global__ __launch_bounds__(256) void k_mlp_r19(unsigned short* __restrict__ Eh,
                                                 const unsigned short* __restrict__ LEh,
                                                 const void* __restrict__ W1,
                                                 const void* __restrict__ B1,
                                                 const void* __restrict__ W2,
                                                 const void* __restrict__ B2,
                                                 const int* __restrict__ fl, int layer) {
    __shared__ float4 XA[4][16];   // per-wave slot: LE (64 floats)
    __shared__ float4 XB[4][16];   // per-wave slot: E
    const int fbf  = fl[0];
    const int wofs = layer * EMBED * EMBED;
    const int bofs = layer * EMBED;
    const int lane = threadIdx.x & 63;
    const int w    = threadIdx.x >> 6;

    float w1r[64], w12r[64];
    if (fbf) {
        const unsigned short* p1 = (const unsigned short*)W1 + wofs + lane * 64;
        const unsigned short* p2 = (const unsigned short*)W2 + wofs + lane * 64;
        #pragma unroll
        for (int t = 0; t < 16; ++t) {
            ushort4 a = reinterpret_cast<const ushort4*>(p1)[t];
            ushort4 b = reinterpret_cast<const ushort4*>(p2)[t];
            float f0 = bf2f(a.x), f1 = bf2f(a.y), f2 = bf2f(a.z), f3 = bf2f(a.w);
            w1r[4*t+0] = f0; w1r[4*t+1] = f1; w1r[4*t+2] = f2; w1r[4*t+3] = f3;
            w12r[4*t+0] = f0 + bf2f(b.x); w12r[4*t+1] = f1 + bf2f(b.y);
            w12r[4*t+2] = f2 + bf2f(b.z); w12r[4*t+3] = f3 + bf2f(b.w);
        }
    } else {
        const float* p1 = (const float*)W1 + wofs + lane * 64;
        const float* p2 = (const float*)W2 + wofs + lane * 64;
        #pragma unroll
        for (int t = 0; t < 16; ++t) {
            float4 a = reinterpret_cast<const float4*>(p1)[t];
            float4 b = reinterpret_cast<const float4*>(p2)[t];
            w1r[4*t+0] = a.x; w1r[4*t+1] = a.y; w1r[4*t+2] = a.z; w1r[4*t+3] = a.w;
            w12r[4*t+0] = a.x + b.x; w12r[4*t+1] = a.y + b.y;
            w12r[4*t+2] = a.z + b.z; w12r[4*t+3] = a.w + b.w;
        }
    }
    const float bias = getf(B1, bofs + lane, fbf) + getf(B2, bofs + lane, fbf);

    const int gw = blockIdx.x * 4 + w;
    const int nw = gridDim.x * 4;

    int row = gw;
    float le = 0.0f, ee = 0.0f;
    if (row < N_NODES) {
        le = h2f(LEh[row * EMBED + lane]);
        ee = h2f(Eh[row * EMBED + lane]);
    }
    while (row < N_NODES) {
        const int nrow = row + nw;
        float nle = 0.0f, nee = 0.0f;
        if (nrow < N_NODES) {
            nle = h2f(LEh[nrow * EMBED + lane]);
            nee = h2f(Eh[nrow * EMBED + lane]);
        }

        ((float*)&XA[w][0])[lane] = le;   // LE  -> w12r
        ((float*)&XB[w][0])[lane] = ee;   // E   -> w1r
        float acc0 = bias, acc1 = 0.0f;
        #pragma unroll
        for (int t = 0; t < 16; ++t) {
            float4 a = XA[w][t];   // wave-uniform ds_read_b128 broadcast
            float4 b = XB[w][t];
            acc0 = fmaf(a.x, w12r[4*t+0], acc0);
            acc1 = fmaf(b.x, w1r [4*t+0], acc1);
            acc0 = fmaf(a.y, w12r[4*t+1], acc0);
            acc1 = fmaf(b.y, w1r [4*t+1], acc1);
            acc0 = fmaf(a.z, w12r[4*t+2], acc0);
            acc1 = fmaf(b.z, w1r [4*t+2], acc1);
            acc0 = fmaf(a.w, w12r[4*t+3], acc0);
            acc1 = fmaf(b.w, w1r [4*t+3], acc1);
        }
        float acc = acc0 + acc1;
        float h = (acc > 0.0f) ? acc : 0.2f * acc;

        float s = h * h;
        #pragma unroll
        for (int d = 1; d < 64; d <<= 1) s += __shfl_xor(s, d, 64);
        const float inv = 1.0f / fmaxf(sqrtf(s), 1e-12f);

        Eh[row * EMBED + lane] = f2h(h * inv);

        row = nrow; le = nle; ee = nee;
    }
}

// -------- gather batch rows into FLOAT output --------
__global__ void k_pick_r19(const unsigned short* __restrict__ Eh, const void* __restrict__ bu,
                           const void* __restrict__ bp, const void* __restrict__ bn,
                           const int* __restrict__ fl,
                           float* __restrict__ out, int stage) {
    int i64 = fl[1];
    int i = blockIdx.x * 256 + threadIdx.x;
    if (i >= 3 * BATCH * EMBED) return;
    int c = i & 63;
    int row = i >> 6;
    int o = row >> 12;
    int b = row & 4095;
    int idx;
    if (o == 0)      idx = geti(bu, b, i64);
    else if (o == 1) idx = geti(bp, b, i64);
    else             idx = geti(bn, b, i64);
    int src;
    if (o == 0) src = clampi(idx, 0, NUM_USERS - 1);
    else        src = NUM_USERS + clampi(idx, 0, NUM_ITEMS - 1);
    int pos = o * (BATCH * 256) + b * 256 + stage * 64 + c;
    out[pos] = h2f(Eh[src * EMBED + c]);
}

// -------- launch --------
extern "C" void kernel_launch(void* const* d_in, const int* in_sizes, int n_in,
                              void* d_out, int out_size, void* d_ws, size_t ws_size,
                              hipStream_t stream) {
    const void* edge_val = d_in[0];
    const void* emb_u    = d_in[1];
    const void* emb_i    = d_in[2];
    const void* W1w      = d_in[3];
    const void* W1b      = d_in[4];
    const void* W2w      = d_in[5];
    const void* W2b      = d_in[6];
    const void* erow     = d_in[7];
    const void* ecol     = d_in[8];
    const void* bu       = d_in[9];
    const void* bp       = d_in[10];
    const void* bn       = d_in[11];

    const size_t EHB  = (size_t)N_NODES * EMBED * 2;   // 19.2 MB fp16 E
    const size_t RPB  = 600064;                         // rowptr
    const size_t CNB  = 600064;                         // cnt/cursor
    const size_t BSB  = 4096;                           // block sums
    const size_t CVB2 = (size_t)NNZ * sizeof(int2);     // 19.2 MB packed (c,v)

    const size_t need = 256 + 2 * EHB + RPB + CNB + BSB + CVB2;   // ~59 MB
    if (ws_size < need) return;   // zero-output signature

    char* ws = (char*)d_ws;
    int*            fl     = (int*)ws;
    unsigned short* Eh     = (unsigned short*)(ws + 256);
    unsigned short* LEh    = (unsigned short*)(ws + 256 + EHB);
    int*            rowptr = (int*)(ws + 256 + 2 * EHB);
    int*            cnt    = (int*)(ws + 256 + 2 * EHB + RPB);
    int*            bsum   = (int*)(ws + 256 + 2 * EHB + RPB + CNB);
    int2*           colcv  = (int2*)(ws + 256 + 2 * EHB + RPB + CNB + BSB);
    float*          out    = (float*)d_out;

    k_flags_r19<<<1, 64, 0, stream>>>((const unsigned short*)edge_val, erow, fl);

    k_init_r19<<<(N_NODES * EMBED + 255) / 256, 256, 0, stream>>>(emb_u, emb_i, fl, Eh);

    hipMemsetAsync(cnt, 0, CNB, stream);
    k_count_r19<<<(NNZ + 255) / 256, 256, 0, stream>>>(erow, fl, cnt);
    k_scanA_r19<<<NB, 256, 0, stream>>>(cnt, bsum);
    k_scanB_r19<<<1, 1024, 0, stream>>>(bsum);
    k_scanC_r19<<<NB, 256, 0, stream>>>(cnt, bsum, rowptr);
    hipMemsetAsync(cnt, 0, CNB, stream);
    k_scatter_r19<<<(NNZ + 255) / 256, 256, 0, stream>>>(edge_val, erow, ecol, fl,
                                                         rowptr, cnt, colcv);

    k_pick_r19<<<(3 * BATCH * EMBED + 255) / 256, 256, 0, stream>>>(Eh, bu, bp, bn, fl, out, 0);

    for (int l = 0; l < 3; ++l) {
        k_gath_r19<<<(N_NODES + 3) / 4, 256, 0, stream>>>(rowptr, colcv, Eh, LEh);
        k_mlp_r19<<<1280, 256, 0, stream>>>(Eh, LEh, W1w, W1b, W2w, W2b, fl, l);
        k_pick_r19<<<(3 * BATCH * EMBED + 255) / 256, 256, 0, stream>>>(Eh, bu, bp, bn, fl, out, l + 1);
    }
}